// Round 10
// baseline (127.644 us; speedup 1.0000x reference)
//
#include <hip/hip_runtime.h>
#include <hip/hip_bf16.h>

#define B_SZ 8192
#define D_SZ 256
// rows pre-scaled by sqrt(log2(e)/T): exp2(acc) == exp(sim/T)
#define PRESCALE 4.539816004686735f

typedef __attribute__((ext_vector_type(4))) float f32x4;
typedef __attribute__((ext_vector_type(8))) short s16x8;

// ---- async global->LDS, 16B per lane (wave-uniform LDS base + lane*16) ----
__device__ __forceinline__ void async_copy16(const void* g, void* l) {
    __builtin_amdgcn_global_load_lds(
        (const __attribute__((address_space(1))) unsigned int*)g,
        (__attribute__((address_space(3))) unsigned int*)l,
        16, 0, 0);
}

// ---------------- L2-normalize rows, scale, cast to bf16 (+ zero sums) -----
__global__ __launch_bounds__(256) void norm_kernel(const float* __restrict__ emb,
                                                   ushort* __restrict__ nbf,
                                                   float* __restrict__ sums) {
    if (blockIdx.x < 64) sums[blockIdx.x * 256 + threadIdx.x] = 0.0f;

    int wave = threadIdx.x >> 6, lane = threadIdx.x & 63;
    int row  = blockIdx.x * 4 + wave;
    const float4 v = ((const float4*)(emb + (size_t)row * D_SZ))[lane];
    float ss = v.x * v.x + v.y * v.y + v.z * v.z + v.w * v.w;
    #pragma unroll
    for (int m = 1; m < 64; m <<= 1) ss += __shfl_xor(ss, m, 64);
    float s = PRESCALE / fmaxf(sqrtf(ss), 1e-12f);
    __hip_bfloat16 b0 = __float2bfloat16(v.x * s);
    __hip_bfloat16 b1 = __float2bfloat16(v.y * s);
    __hip_bfloat16 b2 = __float2bfloat16(v.z * s);
    __hip_bfloat16 b3 = __float2bfloat16(v.w * s);
    ushort4 o;
    o.x = *(ushort*)&b0; o.y = *(ushort*)&b1; o.z = *(ushort*)&b2; o.w = *(ushort*)&b3;
    ((ushort4*)(nbf + (size_t)row * D_SZ))[lane] = o;
}

// ---------------- fused sim tile: upper triangle, double-buffered matmul ---
// 128x128 tile, 256 threads = 4 waves (2x2), BK=64, mfma 16x16x32 bf16.
// DOUBLE-BUFFERED LDS: stage kk+1 is issued BEFORE computing stage kk, so the
// vmcnt(0) drain at each barrier waits on loads that aged a full compute
// phase. 5 barriers/block (was 9). LDS 64 KB -> 2 blocks/CU.
// XOR-swizzled staging (slot c of row r holds chunk c^(r&7)) -> ~0 conflicts.
// Epilogue partials [128][32] include wx in column -> unique writer (no race).
__global__ __launch_bounds__(256) void sim_kernel(const ushort* __restrict__ N,
                                                  const int* __restrict__ ids,
                                                  float* __restrict__ all_sum,
                                                  float* __restrict__ pos_sum) {
    __shared__ ushort sA[2][128 * 64];   // [0] reused as rowAll partials
    __shared__ ushort sB[2][128 * 64];   // [0] reused as rowPos partials

    const int t    = threadIdx.x;
    const int wave = t >> 6, lane = t & 63;
    const int wy   = wave >> 1, wx = wave & 1;

    // decode upper-triangular tile pair: tb = bj*(bj+1)/2 + bi, bi <= bj
    int tb = blockIdx.x;
    int bj = (int)((sqrtf(8.0f * tb + 1.0f) - 1.0f) * 0.5f);
    while ((bj + 1) * (bj + 2) / 2 <= tb) ++bj;
    while (bj * (bj + 1) / 2 > tb) --bj;
    const int bi   = tb - bj * (bj + 1) / 2;
    const int i0   = bi * 128;
    const int j0   = bj * 128;
    const bool diag = (bi == bj);

    f32x4 acc[4][4];
    #pragma unroll
    for (int mi = 0; mi < 4; ++mi)
        #pragma unroll
        for (int ni = 0; ni < 4; ++ni)
            acc[mi][ni] = (f32x4){0.f, 0.f, 0.f, 0.f};

    const int r   = lane >> 3;                      // 0..7 sub-row
    const int c8s = ((lane & 7) ^ r) * 8;           // swizzled source chunk

    const ushort* gA = N + (size_t)(i0 + wave * 32) * D_SZ;
    const ushort* gB = N + (size_t)(j0 + wave * 32) * D_SZ;

    // prologue: stage 0 into buffer 0
    #pragma unroll
    for (int q = 0; q < 4; ++q) {
        async_copy16(gA + (size_t)(q * 8 + r) * D_SZ + c8s, &sA[0][(wave * 32 + q * 8) * 64]);
        async_copy16(gB + (size_t)(q * 8 + r) * D_SZ + c8s, &sB[0][(wave * 32 + q * 8) * 64]);
    }

    #pragma unroll
    for (int kk = 0; kk < 4; ++kk) {
        __syncthreads();   // drains vmcnt -> buffer kk&1 ready
        const int buf = kk & 1;
        if (kk < 3) {
            // prefetch next stage into the other buffer (consumed 2 stages ago)
            const int k0 = (kk + 1) * 64;
            const int nb = buf ^ 1;
            #pragma unroll
            for (int q = 0; q < 4; ++q) {
                async_copy16(gA + (size_t)(q * 8 + r) * D_SZ + k0 + c8s,
                             &sA[nb][(wave * 32 + q * 8) * 64]);
                async_copy16(gB + (size_t)(q * 8 + r) * D_SZ + k0 + c8s,
                             &sB[nb][(wave * 32 + q * 8) * 64]);
            }
        }
        #pragma unroll
        for (int ks = 0; ks < 2; ++ks) {
            const int C = ks * 4 + (lane >> 4);     // k-chunk index 0..7
            const int slot = (C ^ (lane & 7)) * 8;  // un-swizzle
            s16x8 af[4], bf[4];
            #pragma unroll
            for (int mi = 0; mi < 4; ++mi)
                af[mi] = *(const s16x8*)&sA[buf][(wy * 64 + mi * 16 + (lane & 15)) * 64 + slot];
            #pragma unroll
            for (int ni = 0; ni < 4; ++ni)
                bf[ni] = *(const s16x8*)&sB[buf][(wx * 64 + ni * 16 + (lane & 15)) * 64 + slot];
            #pragma unroll
            for (int mi = 0; mi < 4; ++mi)
                #pragma unroll
                for (int ni = 0; ni < 4; ++ni)
                    acc[mi][ni] = __builtin_amdgcn_mfma_f32_16x16x32_bf16(
                        af[mi], bf[ni], acc[mi][ni], 0, 0, 0);
        }
    }
    // NOTE: no barrier here. Last compute read buffers[1]; partials go to
    // buffers[0], which no wave touches after its own kk=2 compute.

    // ---- epilogue.  C/D map: col=lane&15, row=(lane>>4)*4+reg ----
    float* rowAllPart = (float*)sA[0];   // [128][32], col = wx*16+myc (unique writer)
    float* rowPosPart = (float*)sB[0];
    const int myc = lane & 15;

    // column ids for this wave's 64 columns (global, L1-hot, coalesced)
    int idc[4];
    #pragma unroll
    for (int ni = 0; ni < 4; ++ni)
        idc[ni] = ids[j0 + wx * 64 + ni * 16 + myc];

    float cAll[4] = {0.f, 0.f, 0.f, 0.f};
    float cPos[4] = {0.f, 0.f, 0.f, 0.f};

    #pragma unroll
    for (int mi = 0; mi < 4; ++mi) {
        float rAll[4] = {0.f, 0.f, 0.f, 0.f};
        float rPos[4] = {0.f, 0.f, 0.f, 0.f};
        const int rbase = wy * 64 + mi * 16 + (lane >> 4) * 4;
        const int4 idr  = *(const int4*)&ids[i0 + rbase];   // 16B aligned
        #pragma unroll
        for (int ni = 0; ni < 4; ++ni) {
            const int cloc = wx * 64 + ni * 16 + myc;
            #pragma unroll
            for (int rg = 0; rg < 4; ++rg) {
                const int lr = rbase + rg;
                float e = __builtin_amdgcn_exp2f(acc[mi][ni][rg]);
                if (diag && lr == cloc) e = 0.0f;        // diagonal element
                rAll[rg] += e; cAll[ni] += e;
                const int idrv = (rg == 0) ? idr.x : (rg == 1) ? idr.y
                               : (rg == 2) ? idr.z : idr.w;
                if (idrv == idc[ni]) { rPos[rg] += e; cPos[ni] += e; }
            }
        }
        #pragma unroll
        for (int rg = 0; rg < 4; ++rg) {
            rowAllPart[(rbase + rg) * 32 + wx * 16 + myc] = rAll[rg];
            rowPosPart[(rbase + rg) * 32 + wx * 16 + myc] = rPos[rg];
        }
    }

    // column sums -> rows j (off-diagonal tiles only; symmetry)
    if (!diag) {
        #pragma unroll
        for (int ni = 0; ni < 4; ++ni) {
            cAll[ni] += __shfl_xor(cAll[ni], 16, 64);
            cAll[ni] += __shfl_xor(cAll[ni], 32, 64);
            cPos[ni] += __shfl_xor(cPos[ni], 16, 64);
            cPos[ni] += __shfl_xor(cPos[ni], 32, 64);
        }
        if (lane < 16) {
            #pragma unroll
            for (int ni = 0; ni < 4; ++ni) {
                const int gc = j0 + wx * 64 + ni * 16 + lane;
                atomicAdd(&all_sum[gc], cAll[ni]);
                atomicAdd(&pos_sum[gc], cPos[ni]);
            }
        }
    }

    __syncthreads();
    // row partial reduce: thread t -> (row = t&127, array = t>>7).
    {
        const int row = t & 127;
        const float* src = (t >= 128) ? rowPosPart : rowAllPart;
        float s = 0.0f;
        #pragma unroll
        for (int k8 = 0; k8 < 8; ++k8) {
            const int chunk = (k8 + (row & 7)) & 7;
            const float4 v = *(const float4*)&src[row * 32 + chunk * 4];
            s += v.x + v.y + v.z + v.w;
        }
        float* dst = (t >= 128) ? pos_sum : all_sum;
        atomicAdd(&dst[i0 + row], s);
    }
}

// ---------------- final scalar reduce ----------------
__global__ __launch_bounds__(256) void loss_kernel(const float* __restrict__ all_sum,
                                                   const float* __restrict__ pos_sum,
                                                   float* __restrict__ out) {
    float loss = 0.0f, cnt = 0.0f;
    for (int i = threadIdx.x; i < B_SZ; i += 256) {
        float p = pos_sum[i], a = all_sum[i];
        if (p > 0.0f) { loss += logf(a) - logf(p); cnt += 1.0f; }
    }
    #pragma unroll
    for (int m = 1; m < 64; m <<= 1) {
        loss += __shfl_xor(loss, m, 64);
        cnt  += __shfl_xor(cnt, m, 64);
    }
    __shared__ float sl[4], sc[4];
    int wave = threadIdx.x >> 6, lane = threadIdx.x & 63;
    if (lane == 0) { sl[wave] = loss; sc[wave] = cnt; }
    __syncthreads();
    if (threadIdx.x == 0) {
        float L = sl[0] + sl[1] + sl[2] + sl[3];
        float C = sc[0] + sc[1] + sc[2] + sc[3];
        out[0] = L / fmaxf(C, 1.0f);
    }
}

extern "C" void kernel_launch(void* const* d_in, const int* in_sizes, int n_in,
                              void* d_out, int out_size, void* d_ws, size_t ws_size,
                              hipStream_t stream) {
    const float* emb = (const float*)d_in[0];
    const int*   ids = (const int*)d_in[1];
    float*       out = (float*)d_out;

    float*  all_sum = (float*)d_ws;
    float*  pos_sum = all_sum + B_SZ;
    ushort* nbf     = (ushort*)((char*)d_ws + 65536);   // 8192*256 bf16 = 4 MB

    norm_kernel<<<B_SZ / 4, 256, 0, stream>>>(emb, nbf, all_sum);
    const int ntiles = (B_SZ / 128) * (B_SZ / 128 + 1) / 2;   // 2080
    sim_kernel<<<ntiles, 256, 0, stream>>>(nbf, ids, all_sum, pos_sum);
    loss_kernel<<<1, 256, 0, stream>>>(all_sum, pos_sum, out);
}

// Round 11
// 123.951 us; speedup vs baseline: 1.0298x; 1.0298x over previous
//
#include <hip/hip_runtime.h>
#include <hip/hip_bf16.h>

#define B_SZ 8192
#define D_SZ 256
#define NTILES 2080   // (8192/128)*(8192/128+1)/2 upper-tri tiles
// rows pre-scaled by sqrt(log2(e)/T): exp2(acc) == exp(sim/T)
#define PRESCALE 4.539816004686735f

typedef __attribute__((ext_vector_type(4))) float f32x4;
typedef __attribute__((ext_vector_type(8))) short s16x8;

// ---- async global->LDS, 16B per lane (wave-uniform LDS base + lane*16) ----
__device__ __forceinline__ void async_copy16(const void* g, void* l) {
    __builtin_amdgcn_global_load_lds(
        (const __attribute__((address_space(1))) unsigned int*)g,
        (__attribute__((address_space(3))) unsigned int*)l,
        16, 0, 0);
}

// ---------------- L2-normalize rows, scale, cast to bf16 (+ zero sums) -----
// PERSISTENT: 256 blocks grid-stride over 2048 row-groups (dispatch-rate
// theory: 2048-block launch costs ~44 us of pure WG dispatch at ~46 WG/us).
__global__ __launch_bounds__(256) void norm_kernel(const float* __restrict__ emb,
                                                   ushort* __restrict__ nbf,
                                                   float* __restrict__ sums) {
    const int wave = threadIdx.x >> 6, lane = threadIdx.x & 63;
    // zero all_sum+pos_sum: 16384 floats over 256 blocks
    sums[blockIdx.x * 64 + (threadIdx.x >> 2) ] = 0.0f;   // 64 per block x256 = 16384

    for (int g = blockIdx.x; g < B_SZ / 4; g += 256) {
        const int row = g * 4 + wave;
        const float4 v = ((const float4*)(emb + (size_t)row * D_SZ))[lane];
        float ss = v.x * v.x + v.y * v.y + v.z * v.z + v.w * v.w;
        #pragma unroll
        for (int m = 1; m < 64; m <<= 1) ss += __shfl_xor(ss, m, 64);
        float s = PRESCALE / fmaxf(sqrtf(ss), 1e-12f);
        __hip_bfloat16 b0 = __float2bfloat16(v.x * s);
        __hip_bfloat16 b1 = __float2bfloat16(v.y * s);
        __hip_bfloat16 b2 = __float2bfloat16(v.z * s);
        __hip_bfloat16 b3 = __float2bfloat16(v.w * s);
        ushort4 o;
        o.x = *(ushort*)&b0; o.y = *(ushort*)&b1; o.z = *(ushort*)&b2; o.w = *(ushort*)&b3;
        ((ushort4*)(nbf + (size_t)row * D_SZ))[lane] = o;
    }
}

// ---------------- fused sim tiles: upper triangle, PERSISTENT blocks -------
// r9 body (best measured structure: 45.4 us) wrapped in a grid-stride tile
// loop. 1024 blocks instead of 2080 -> dispatch amortized, residency
// self-sustaining. 128x128 tile, 4 waves (2x2), BK=64, XOR-swizzled staging,
// LDS 32 KB, race-free [128][32] epilogue partials.
__global__ __launch_bounds__(256) void sim_kernel(const ushort* __restrict__ N,
                                                  const int* __restrict__ ids,
                                                  float* __restrict__ all_sum,
                                                  float* __restrict__ pos_sum) {
    __shared__ ushort sA[128 * 64];   // staging; reused as rowAll partials [128][32] f32
    __shared__ ushort sB[128 * 64];   // staging; reused as rowPos partials [128][32] f32

    const int t    = threadIdx.x;
    const int wave = t >> 6, lane = t & 63;
    const int wy   = wave >> 1, wx = wave & 1;
    const int r    = lane >> 3;                     // 0..7 sub-row
    const int c8s  = ((lane & 7) ^ r) * 8;          // swizzled source chunk
    const int myc  = lane & 15;

    for (int tb = blockIdx.x; tb < NTILES; tb += (int)gridDim.x) {
        // decode upper-triangular tile pair: tb = bj*(bj+1)/2 + bi, bi <= bj
        int bj = (int)((sqrtf(8.0f * tb + 1.0f) - 1.0f) * 0.5f);
        while ((bj + 1) * (bj + 2) / 2 <= tb) ++bj;
        while (bj * (bj + 1) / 2 > tb) --bj;
        const int bi   = tb - bj * (bj + 1) / 2;
        const int i0   = bi * 128;
        const int j0   = bj * 128;
        const bool diag = (bi == bj);

        f32x4 acc[4][4];
        #pragma unroll
        for (int mi = 0; mi < 4; ++mi)
            #pragma unroll
            for (int ni = 0; ni < 4; ++ni)
                acc[mi][ni] = (f32x4){0.f, 0.f, 0.f, 0.f};

        for (int kk = 0; kk < 4; ++kk) {
            const int k0 = kk * 64;
            const ushort* gA = N + (size_t)(i0 + wave * 32) * D_SZ + k0;
            const ushort* gB = N + (size_t)(j0 + wave * 32) * D_SZ + k0;
            #pragma unroll
            for (int q = 0; q < 4; ++q) {
                async_copy16(gA + (size_t)(q * 8 + r) * D_SZ + c8s, &sA[(wave * 32 + q * 8) * 64]);
                async_copy16(gB + (size_t)(q * 8 + r) * D_SZ + c8s, &sB[(wave * 32 + q * 8) * 64]);
            }
            __syncthreads();

            #pragma unroll
            for (int ks = 0; ks < 2; ++ks) {
                const int C = ks * 4 + (lane >> 4);     // k-chunk index 0..7
                const int slot = (C ^ (lane & 7)) * 8;  // un-swizzle
                s16x8 af[4], bf[4];
                #pragma unroll
                for (int mi = 0; mi < 4; ++mi)
                    af[mi] = *(const s16x8*)&sA[(wy * 64 + mi * 16 + (lane & 15)) * 64 + slot];
                #pragma unroll
                for (int ni = 0; ni < 4; ++ni)
                    bf[ni] = *(const s16x8*)&sB[(wx * 64 + ni * 16 + (lane & 15)) * 64 + slot];
                #pragma unroll
                for (int mi = 0; mi < 4; ++mi)
                    #pragma unroll
                    for (int ni = 0; ni < 4; ++ni)
                        acc[mi][ni] = __builtin_amdgcn_mfma_f32_16x16x32_bf16(
                            af[mi], bf[ni], acc[mi][ni], 0, 0, 0);
            }
            __syncthreads();   // last iter: sA/sB free for epilogue reuse
        }

        // ---- epilogue.  C/D map: col=lane&15, row=(lane>>4)*4+reg ----
        float* rowAllPart = (float*)sA;   // [128][32], col = wx*16+myc (unique writer)
        float* rowPosPart = (float*)sB;

        int idc[4];
        #pragma unroll
        for (int ni = 0; ni < 4; ++ni)
            idc[ni] = ids[j0 + wx * 64 + ni * 16 + myc];

        float cAll[4] = {0.f, 0.f, 0.f, 0.f};
        float cPos[4] = {0.f, 0.f, 0.f, 0.f};

        #pragma unroll
        for (int mi = 0; mi < 4; ++mi) {
            float rAll[4] = {0.f, 0.f, 0.f, 0.f};
            float rPos[4] = {0.f, 0.f, 0.f, 0.f};
            const int rbase = wy * 64 + mi * 16 + (lane >> 4) * 4;
            const int4 idr  = *(const int4*)&ids[i0 + rbase];   // 16B aligned
            #pragma unroll
            for (int ni = 0; ni < 4; ++ni) {
                const int cloc = wx * 64 + ni * 16 + myc;
                #pragma unroll
                for (int rg = 0; rg < 4; ++rg) {
                    const int lr = rbase + rg;
                    float e = __builtin_amdgcn_exp2f(acc[mi][ni][rg]);
                    if (diag && lr == cloc) e = 0.0f;        // diagonal element
                    rAll[rg] += e; cAll[ni] += e;
                    const int idrv = (rg == 0) ? idr.x : (rg == 1) ? idr.y
                                   : (rg == 2) ? idr.z : idr.w;
                    if (idrv == idc[ni]) { rPos[rg] += e; cPos[ni] += e; }
                }
            }
            #pragma unroll
            for (int rg = 0; rg < 4; ++rg) {
                rowAllPart[(rbase + rg) * 32 + wx * 16 + myc] = rAll[rg];
                rowPosPart[(rbase + rg) * 32 + wx * 16 + myc] = rPos[rg];
            }
        }

        // column sums -> rows j (off-diagonal tiles only; symmetry)
        if (!diag) {
            #pragma unroll
            for (int ni = 0; ni < 4; ++ni) {
                cAll[ni] += __shfl_xor(cAll[ni], 16, 64);
                cAll[ni] += __shfl_xor(cAll[ni], 32, 64);
                cPos[ni] += __shfl_xor(cPos[ni], 16, 64);
                cPos[ni] += __shfl_xor(cPos[ni], 32, 64);
            }
            if (lane < 16) {
                #pragma unroll
                for (int ni = 0; ni < 4; ++ni) {
                    const int gc = j0 + wx * 64 + ni * 16 + lane;
                    atomicAdd(&all_sum[gc], cAll[ni]);
                    atomicAdd(&pos_sum[gc], cPos[ni]);
                }
            }
        }

        __syncthreads();
        // row partial reduce: thread t -> (row = t&127, array = t>>7)
        {
            const int row = t & 127;
            const float* src = (t >= 128) ? rowPosPart : rowAllPart;
            float s = 0.0f;
            #pragma unroll
            for (int k8 = 0; k8 < 8; ++k8) {
                const int chunk = (k8 + (row & 7)) & 7;
                const float4 v = *(const float4*)&src[row * 32 + chunk * 4];
                s += v.x + v.y + v.z + v.w;
            }
            float* dst = (t >= 128) ? pos_sum : all_sum;
            atomicAdd(&dst[i0 + row], s);
        }
        __syncthreads();   // partials consumed before next tile's staging
    }
}

// ---------------- final scalar reduce ----------------
__global__ __launch_bounds__(256) void loss_kernel(const float* __restrict__ all_sum,
                                                   const float* __restrict__ pos_sum,
                                                   float* __restrict__ out) {
    float loss = 0.0f, cnt = 0.0f;
    for (int i = threadIdx.x; i < B_SZ; i += 256) {
        float p = pos_sum[i], a = all_sum[i];
        if (p > 0.0f) { loss += logf(a) - logf(p); cnt += 1.0f; }
    }
    #pragma unroll
    for (int m = 1; m < 64; m <<= 1) {
        loss += __shfl_xor(loss, m, 64);
        cnt  += __shfl_xor(cnt, m, 64);
    }
    __shared__ float sl[4], sc[4];
    int wave = threadIdx.x >> 6, lane = threadIdx.x & 63;
    if (lane == 0) { sl[wave] = loss; sc[wave] = cnt; }
    __syncthreads();
    if (threadIdx.x == 0) {
        float L = sl[0] + sl[1] + sl[2] + sl[3];
        float C = sc[0] + sc[1] + sc[2] + sc[3];
        out[0] = L / fmaxf(C, 1.0f);
    }
}

extern "C" void kernel_launch(void* const* d_in, const int* in_sizes, int n_in,
                              void* d_out, int out_size, void* d_ws, size_t ws_size,
                              hipStream_t stream) {
    const float* emb = (const float*)d_in[0];
    const int*   ids = (const int*)d_in[1];
    float*       out = (float*)d_out;

    float*  all_sum = (float*)d_ws;
    float*  pos_sum = all_sum + B_SZ;
    ushort* nbf     = (ushort*)((char*)d_ws + 65536);   // 8192*256 bf16 = 4 MB

    norm_kernel<<<256, 256, 0, stream>>>(emb, nbf, all_sum);
    sim_kernel<<<1024, 256, 0, stream>>>(nbf, ids, all_sum, pos_sum);
    loss_kernel<<<1, 256, 0, stream>>>(all_sum, pos_sum, out);
}